// Round 9
// baseline (44.764 us; speedup 1.0000x reference)
//
#include <hip/hip_runtime.h>
#include <hip/hip_bf16.h>

#define NN 96
// tanh(x) = 1 - 2/(exp2(C*x)+1), C = 2*log2(e)
#define C_TANH 2.8853900817779268f

typedef __attribute__((ext_vector_type(4))) float    f32x4;
typedef __attribute__((ext_vector_type(2))) float    f32x2;
typedef __attribute__((ext_vector_type(8))) short    short8;
typedef __attribute__((ext_vector_type(8))) _Float16 half8;

// v_cvt_pk_bf16_f32: dst.lo16 = bf16(lo), dst.hi16 = bf16(hi), RNE
static __device__ inline unsigned int cvt_pk_bf16(float lo, float hi) {
    unsigned int r;
    asm("v_cvt_pk_bf16_f32 %0, %1, %2" : "=v"(r) : "v"(lo), "v"(hi));
    return r;
}

// ---------------------------------------------------------------------------
// K1: fused cvt + bf16 MFMA GEMM + exp epilogue. (unchanged from R8)
//   n < 512 : Ea[m, n]     = fp16( 2^( C * (X·W1row_n)[cols 0:512] ) )
//   n >= 512: Eh[m, n-512] = fp16( 2^( C * ((X·W1row_{n-512})[cols 512:] + b1) ) )
// 768 blocks; XCD-swizzle: xcd = bid&7 owns M-rows [xcd*384, +384) x all N.
// T14 async-stage split: RA/RB register ping-pong, loads 2 k-steps ahead.
// ---------------------------------------------------------------------------
__global__ __launch_bounds__(256) void gemm_h(const float* __restrict__ X,
                                              const float* __restrict__ W1,
                                              const float* __restrict__ b1,
                                              _Float16* __restrict__ Ea,
                                              _Float16* __restrict__ Eh) {
    __shared__ unsigned short As[2][2048];   // 4KB each buffer
    __shared__ unsigned short Bs[2][2048];

    int bid  = blockIdx.x;
    int xcd  = bid & 7;
    int sub  = bid >> 3;                 // 0..95
    int mloc = sub % 6;
    int nq   = sub / 6;                  // 0..15
    int mb   = (xcd * 6 + mloc) * 64;
    int nb   = nq * 64;
    int tid = threadIdx.x;
    int w   = tid >> 6;
    int l   = tid & 63;

    // staging geometry: thread -> (row 0..63, 8-f32 group 0..3)
    int srow = tid >> 2;
    int sg   = (tid & 3) * 8;
    int scs  = sg ^ ((srow & 3) << 3);       // swizzled short offset in row
    const float* asrc = X + (mb + srow) * 512 + sg;
    int nrow = nb + srow;
    const float* bsrc = W1 + (nrow & 511) * 1024 + ((nrow >> 9) << 9) + sg;
    unsigned short* adst = &As[0][srow * 32 + scs];
    unsigned short* bdst = &Bs[0][srow * 32 + scs];

    struct Regs { f32x4 a0, a1, b0, b4; };
    Regs RA, RB;

#define LOADR(R, k0)                                                          \
    {                                                                         \
        R.a0 = *(const f32x4*)(asrc + (k0));                                  \
        R.a1 = *(const f32x4*)(asrc + (k0) + 4);                              \
        R.b0 = *(const f32x4*)(bsrc + (k0));                                  \
        R.b4 = *(const f32x4*)(bsrc + (k0) + 4);                              \
    }
#define WRITER(R, buf)                                                        \
    {                                                                         \
        uint4 ua, ub;                                                         \
        ua.x = cvt_pk_bf16(R.a0[0], R.a0[1]); ua.y = cvt_pk_bf16(R.a0[2], R.a0[3]); \
        ua.z = cvt_pk_bf16(R.a1[0], R.a1[1]); ua.w = cvt_pk_bf16(R.a1[2], R.a1[3]); \
        ub.x = cvt_pk_bf16(R.b0[0], R.b0[1]); ub.y = cvt_pk_bf16(R.b0[2], R.b0[3]); \
        ub.z = cvt_pk_bf16(R.b4[0], R.b4[1]); ub.w = cvt_pk_bf16(R.b4[2], R.b4[3]); \
        *(uint4*)(adst + (buf) * 2048) = ua;                                  \
        *(uint4*)(bdst + (buf) * 2048) = ub;                                  \
    }

    int lr    = l & 15;
    int koffs = ((l >> 4) * 8) ^ ((lr & 3) << 3);   // swizzled k-chunk
    int aoff  = (16 * w + lr) * 32 + koffs;
    int boff0 = lr * 32 + koffs;

    f32x4 acc[4] = {};

#define COMPUTE(cur)                                                          \
    {                                                                         \
        short8 afr = *(const short8*)(&As[cur][aoff]);                        \
        short8 bfr[4];                                                        \
        _Pragma("unroll")                                                     \
        for (int t = 0; t < 4; ++t)                                           \
            bfr[t] = *(const short8*)(&Bs[cur][boff0 + t * 512]);             \
        _Pragma("unroll")                                                     \
        for (int t = 0; t < 4; ++t)                                           \
            acc[t] = __builtin_amdgcn_mfma_f32_16x16x32_bf16(afr, bfr[t],     \
                                                             acc[t], 0, 0, 0);\
    }

    // pipeline: LOADR 2 ahead, WRITER 1 ahead, COMPUTE current
    LOADR(RA, 0)
    WRITER(RA, 0)                         // k=0 -> buf0
    LOADR(RB, 32)                         // k=1 in flight
    __syncthreads();
#pragma unroll 1
    for (int kk = 0; kk < 7; ++kk) {      // k = 2kk, 2kk+1
        LOADR(RA, (2 * kk + 2) * 32)
        COMPUTE(0)                        // k = 2kk
        WRITER(RB, 1)                     // k = 2kk+1 (waits its vmcnt)
        __syncthreads();
        LOADR(RB, (2 * kk + 3) * 32)
        COMPUTE(1)                        // k = 2kk+1
        WRITER(RA, 0)                     // k = 2kk+2
        __syncthreads();
    }
    COMPUTE(0)                            // k = 14
    WRITER(RB, 1)                         // k = 15
    __syncthreads();
    COMPUTE(1)                            // k = 15
#undef LOADR
#undef WRITER
#undef COMPUTE

    // epilogue: D lane l -> D[(l>>4)*4+q][l&15]
    int r0 = (l >> 4) * 4;
    bool isB = (nb >= 512);                 // uniform per block
    int colbase = nb & 511;
    _Float16* dst = isB ? Eh : Ea;
#pragma unroll
    for (int t = 0; t < 4; ++t) {
        int col = colbase + 16 * t + lr;
        float bias = isB ? b1[col] : 0.0f;
#pragma unroll
        for (int q = 0; q < 4; ++q) {
            int m = mb + 16 * w + r0 + q;
            float arg = (acc[t][q] + bias) * C_TANH;
            dst[m * 512 + col] = (_Float16)exp2f(arg);
        }
    }
}

// ---------------------------------------------------------------------------
// K2 v5: out[b,i,j] = S - 2 * sum_k w2[k] / (Ea[b,i,k]*Eh[b,j,k] + 1)
// NO LDS staging: Ea/Eh are L2-resident on the matching XCD (written there by
// gemm's swizzle) -- direct global reads; lanes with equal addresses merge in
// the coalescer, ksub lanes read consecutive 16B chunks (full 64B lines).
// Tile 16i x 16j, 256 thr = 4 waves; wave = kq (128k), lane>>4 = ksub (8k
// interleaved), lane&15 = pos -> thread = 4i x 4j x (4 iters x 8k).
// acc reduce: shfl_xor(16,32) within wave, 3KB LDS across waves.
// 8 blocks/CU resident (3KB LDS) -> ~24-32 waves/CU, all latency hidden.
// ---------------------------------------------------------------------------
__global__ __launch_bounds__(256) void arc_kernel(const _Float16* __restrict__ Ea,
                                                  const _Float16* __restrict__ Eh,
                                                  const float* __restrict__ w2,
                                                  const float* __restrict__ b2,
                                                  float* __restrict__ out) {
    __shared__ float red[3][16][16];     // 3 KB

    int bid = blockIdx.x;                // 32 * 6 * 6 = 1152
    int xcd = bid & 7;
    int sub = bid >> 3;                  // 0..143
    int b   = xcd * 4 + sub / 36;
    int r   = sub % 36;
    int it  = r / 6;
    int jt  = r % 6;
    int tid = threadIdx.x;
    int w   = tid >> 6;
    int kq  = __builtin_amdgcn_readfirstlane(w);  // SGPR 0..3
    int l   = tid & 63;
    int pos = l & 15;
    int ip  = pos >> 2;                  // 0..3
    int jp  = pos & 3;                   // 0..3
    int ksub = l >> 4;                   // 0..3

    const _Float16* abase = Ea + (b * NN + it * 16 + ip * 4) * 512 + kq * 128 + ksub * 8;
    const _Float16* hbase = Eh + (b * NN + jt * 16 + jp * 4) * 512 + kq * 128 + ksub * 8;
    const float*    wp    = w2 + kq * 128 + ksub * 8;

    float acc[4][4] = {};

#define PROC(av, hv, acc)                                                     \
    {                                                                         \
        float s0 = __builtin_fmaf((float)av[0], (float)hv[0], 1.0f);          \
        float s1 = __builtin_fmaf((float)av[1], (float)hv[1], 1.0f);          \
        float s2 = __builtin_fmaf((float)av[2], (float)hv[2], 1.0f);          \
        float s3 = __builtin_fmaf((float)av[3], (float)hv[3], 1.0f);          \
        float s4 = __builtin_fmaf((float)av[4], (float)hv[4], 1.0f);          \
        float s5 = __builtin_fmaf((float)av[5], (float)hv[5], 1.0f);          \
        float s6 = __builtin_fmaf((float)av[6], (float)hv[6], 1.0f);          \
        float s7 = __builtin_fmaf((float)av[7], (float)hv[7], 1.0f);          \
        float n0 = __builtin_fmaf(wv1, s0, wv0 * s1);                         \
        float n1 = __builtin_fmaf(wv3, s2, wv2 * s3);                         \
        float n2 = __builtin_fmaf(wv5, s4, wv4 * s5);                         \
        float n3 = __builtin_fmaf(wv7, s6, wv6 * s7);                         \
        acc = __builtin_fmaf(n0, __builtin_amdgcn_rcpf(s0 * s1), acc);        \
        acc = __builtin_fmaf(n1, __builtin_amdgcn_rcpf(s2 * s3), acc);        \
        acc = __builtin_fmaf(n2, __builtin_amdgcn_rcpf(s4 * s5), acc);        \
        acc = __builtin_fmaf(n3, __builtin_amdgcn_rcpf(s6 * s7), acc);        \
    }

#pragma unroll
    for (int itr = 0; itr < 4; ++itr) {
        int ko = itr * 32;               // halves
        half8 av[4], hv[4];
#pragma unroll
        for (int rr = 0; rr < 4; ++rr) {
            av[rr] = *(const half8*)(abase + rr * 512 + ko);
            hv[rr] = *(const half8*)(hbase + rr * 512 + ko);
        }
        f32x4 wlo = *(const f32x4*)(wp + ko);
        f32x4 whi = *(const f32x4*)(wp + ko + 4);
        float wv0 = wlo[0], wv1 = wlo[1], wv2 = wlo[2], wv3 = wlo[3];
        float wv4 = whi[0], wv5 = whi[1], wv6 = whi[2], wv7 = whi[3];
#pragma unroll
        for (int rr = 0; rr < 4; ++rr)
#pragma unroll
            for (int cc = 0; cc < 4; ++cc)
                PROC(av[rr], hv[cc], acc[rr][cc])
    }
#undef PROC

    // reduce over ksub (lanes ^16, ^32 share pos)
#pragma unroll
    for (int rr = 0; rr < 4; ++rr)
#pragma unroll
        for (int cc = 0; cc < 4; ++cc) {
            acc[rr][cc] += __shfl_xor(acc[rr][cc], 16, 64);
            acc[rr][cc] += __shfl_xor(acc[rr][cc], 32, 64);
        }

    // cross-wave partials
    if (w != 0 && l < 16) {
#pragma unroll
        for (int rr = 0; rr < 4; ++rr) {
            f32x4 v = {acc[rr][0], acc[rr][1], acc[rr][2], acc[rr][3]};
            *(f32x4*)(&red[w - 1][pos][rr * 4]) = v;
        }
    }
    __syncthreads();

    if (w == 0) {
        // S = b2 + sum(w2): 8 elems/lane + butterfly (all lanes get total)
        f32x4 v0 = *(const f32x4*)(w2 + l * 8);
        f32x4 v1 = *(const f32x4*)(w2 + l * 8 + 4);
        float sv = (v0[0] + v0[1]) + (v0[2] + v0[3])
                 + (v1[0] + v1[1]) + (v1[2] + v1[3]);
#pragma unroll
        for (int off = 32; off; off >>= 1) sv += __shfl_xor(sv, off, 64);
        float Sv = sv + b2[0];

        if (l < 16) {
#pragma unroll
            for (int rr = 0; rr < 4; ++rr) {
                f32x4 p0 = *(const f32x4*)(&red[0][pos][rr * 4]);
                f32x4 p1 = *(const f32x4*)(&red[1][pos][rr * 4]);
                f32x4 p2 = *(const f32x4*)(&red[2][pos][rr * 4]);
                f32x4 o;
#pragma unroll
                for (int cc = 0; cc < 4; ++cc) {
                    float a = acc[rr][cc] + p0[cc] + p1[cc] + p2[cc];
                    o[cc] = __builtin_fmaf(-2.f, a, Sv);
                }
                int i = it * 16 + ip * 4 + rr;
                int j = jt * 16 + jp * 4;
                *(f32x4*)(out + (b * NN + i) * NN + j) = o;
            }
        }
    }
}

// ---------------------------------------------------------------------------
extern "C" void kernel_launch(void* const* d_in, const int* in_sizes, int n_in,
                              void* d_out, int out_size, void* d_ws, size_t ws_size,
                              hipStream_t stream) {
    (void)in_sizes; (void)n_in; (void)out_size; (void)ws_size;

    const float* X  = (const float*)d_in[0];   // (32, 96, 512)
    const float* W1 = (const float*)d_in[1];   // (512, 1024)
    const float* b1 = (const float*)d_in[2];   // (512,)
    const float* W2 = (const float*)d_in[3];   // (1, 512)
    const float* b2 = (const float*)d_in[4];   // (1,)
    float* out = (float*)d_out;                // (32, 96, 96)

    char* ws = (char*)d_ws;
    _Float16* Ea = (_Float16*)(ws);                // 3,145,728 B
    _Float16* Eh = (_Float16*)(ws + 3145728);      // 3,145,728 B

    gemm_h<<<768, 256, 0, stream>>>(X, W1, b1, Ea, Eh);
    arc_kernel<<<1152, 256, 0, stream>>>(Ea, Eh, W2, b2, out);
}

// Round 11
// 35.167 us; speedup vs baseline: 1.2729x; 1.2729x over previous
//
#include <hip/hip_runtime.h>
#include <hip/hip_bf16.h>

#define NN 96
// tanh(x) = 1 - 2/(exp2(C*x)+1), C = 2*log2(e)
#define C_TANH 2.8853900817779268f

typedef __attribute__((ext_vector_type(4))) float    f32x4;
typedef __attribute__((ext_vector_type(2))) float    f32x2;
typedef __attribute__((ext_vector_type(8))) short    short8;
typedef __attribute__((ext_vector_type(8))) _Float16 half8;

// v_cvt_pk_bf16_f32: dst.lo16 = bf16(lo), dst.hi16 = bf16(hi), RNE
static __device__ inline unsigned int cvt_pk_bf16(float lo, float hi) {
    unsigned int r;
    asm("v_cvt_pk_bf16_f32 %0, %1, %2" : "=v"(r) : "v"(lo), "v"(hi));
    return r;
}

// ---------------------------------------------------------------------------
// K1 v3: fused cvt + bf16 MFMA GEMM + exp epilogue, 128x128 tile.
//   n < 512 : Ea[m, n]     = fp16( 2^( C * (X·W1row_n)[cols 0:512] ) )
//   n >= 512: Eh[m, n-512] = fp16( 2^( C * ((X·W1row_{n-512})[cols 512:] + b1) ) )
// 192 blocks = 24(M) x 8(N); 512 thr = 8 waves; wave = 32M x 64N (2x4 frags).
// XCD-swizzle: xcd = bid&7 owns M-rows [xcd*384, +384) x all N -> per-XCD L2
// traffic ~12MB (was ~24MB at 64x64): X-chunk read 8x, W1 read 3x.
// T14 async-stage split: RA/RB register ping-pong, loads 2 k-steps ahead.
// ---------------------------------------------------------------------------
__global__ __launch_bounds__(512, 2) void gemm_h(const float* __restrict__ X,
                                                 const float* __restrict__ W1,
                                                 const float* __restrict__ b1,
                                                 _Float16* __restrict__ Ea,
                                                 _Float16* __restrict__ Eh) {
    __shared__ unsigned short As[2][4096];   // 8KB each buffer
    __shared__ unsigned short Bs[2][4096];

    int bid  = blockIdx.x;               // 192 = 8 xcd * (3 m x 8 n)
    int xcd  = bid & 7;
    int sub  = bid >> 3;                 // 0..23
    int mloc = sub % 3;
    int nq   = sub / 3;                  // 0..7
    int mb   = (xcd * 3 + mloc) * 128;
    int nb   = nq * 128;
    int tid = threadIdx.x;
    int w   = tid >> 6;                  // 0..7
    int l   = tid & 63;

    // staging geometry: thread -> (row 0..127, 8-f32 group 0..3)
    int srow = tid >> 2;
    int sg   = (tid & 3) * 8;
    int scs  = sg ^ ((srow & 3) << 3);       // swizzled short offset in row
    const float* asrc = X + (mb + srow) * 512 + sg;
    int nrow = nb + srow;
    const float* bsrc = W1 + (nrow & 511) * 1024 + ((nrow >> 9) << 9) + sg;
    unsigned short* adst = &As[0][srow * 32 + scs];
    unsigned short* bdst = &Bs[0][srow * 32 + scs];

    struct Regs { f32x4 a0, a1, b0, b4; };
    Regs RA, RB;

#define LOADR(R, k0)                                                          \
    {                                                                         \
        R.a0 = *(const f32x4*)(asrc + (k0));                                  \
        R.a1 = *(const f32x4*)(asrc + (k0) + 4);                              \
        R.b0 = *(const f32x4*)(bsrc + (k0));                                  \
        R.b4 = *(const f32x4*)(bsrc + (k0) + 4);                              \
    }
#define WRITER(R, buf)                                                        \
    {                                                                         \
        uint4 ua, ub;                                                         \
        ua.x = cvt_pk_bf16(R.a0[0], R.a0[1]); ua.y = cvt_pk_bf16(R.a0[2], R.a0[3]); \
        ua.z = cvt_pk_bf16(R.a1[0], R.a1[1]); ua.w = cvt_pk_bf16(R.a1[2], R.a1[3]); \
        ub.x = cvt_pk_bf16(R.b0[0], R.b0[1]); ub.y = cvt_pk_bf16(R.b0[2], R.b0[3]); \
        ub.z = cvt_pk_bf16(R.b4[0], R.b4[1]); ub.w = cvt_pk_bf16(R.b4[2], R.b4[3]); \
        *(uint4*)(adst + (buf) * 4096) = ua;                                  \
        *(uint4*)(bdst + (buf) * 4096) = ub;                                  \
    }

    int lr    = l & 15;
    int koffs = ((l >> 4) * 8) ^ ((lr & 3) << 3);   // swizzled k-chunk
    int wm    = w >> 1;                  // 0..3 -> 32-row band
    int wn    = w & 1;                   // 0..1 -> 64-col band
    int aoff0 = (32 * wm + lr) * 32 + koffs;        // + mf*16*32
    int boff0 = (64 * wn + lr) * 32 + koffs;        // + t*16*32

    f32x4 acc[2][4] = {};

#define COMPUTE(cur)                                                          \
    {                                                                         \
        short8 afr[2], bfr[4];                                                \
        _Pragma("unroll")                                                     \
        for (int mf = 0; mf < 2; ++mf)                                        \
            afr[mf] = *(const short8*)(&As[cur][aoff0 + mf * 512]);           \
        _Pragma("unroll")                                                     \
        for (int t = 0; t < 4; ++t)                                           \
            bfr[t] = *(const short8*)(&Bs[cur][boff0 + t * 512]);             \
        _Pragma("unroll")                                                     \
        for (int mf = 0; mf < 2; ++mf)                                        \
            _Pragma("unroll")                                                 \
            for (int t = 0; t < 4; ++t)                                       \
                acc[mf][t] = __builtin_amdgcn_mfma_f32_16x16x32_bf16(         \
                    afr[mf], bfr[t], acc[mf][t], 0, 0, 0);                    \
    }

    // pipeline: LOADR 2 ahead, WRITER 1 ahead, COMPUTE current
    LOADR(RA, 0)
    WRITER(RA, 0)                         // k=0 -> buf0
    LOADR(RB, 32)                         // k=1 in flight
    __syncthreads();
#pragma unroll 1
    for (int kk = 0; kk < 7; ++kk) {      // k = 2kk, 2kk+1
        LOADR(RA, (2 * kk + 2) * 32)
        COMPUTE(0)                        // k = 2kk
        WRITER(RB, 1)                     // k = 2kk+1 (waits its vmcnt)
        __syncthreads();
        LOADR(RB, (2 * kk + 3) * 32)
        COMPUTE(1)                        // k = 2kk+1
        WRITER(RA, 0)                     // k = 2kk+2
        __syncthreads();
    }
    COMPUTE(0)                            // k = 14
    WRITER(RB, 1)                         // k = 15
    __syncthreads();
    COMPUTE(1)                            // k = 15
#undef LOADR
#undef WRITER
#undef COMPUTE

    // epilogue: D lane l -> D[(l>>4)*4+q][l&15]
    int r0 = (l >> 4) * 4;
    bool isB = (nb >= 512);                 // uniform per block (nb mult of 128)
    int colbase = nb & 511;
    _Float16* dst = isB ? Eh : Ea;
#pragma unroll
    for (int t = 0; t < 4; ++t) {
        int col = colbase + 64 * wn + 16 * t + lr;
        float bias = isB ? b1[col] : 0.0f;
#pragma unroll
        for (int mf = 0; mf < 2; ++mf)
#pragma unroll
            for (int q = 0; q < 4; ++q) {
                int m = mb + 32 * wm + 16 * mf + r0 + q;
                float arg = (acc[mf][t][q] + bias) * C_TANH;
                dst[m * 512 + col] = (_Float16)exp2f(arg);
            }
    }
}

// ---------------------------------------------------------------------------
// K2 v4 (reverted to R8 -- proven): out[b,i,j] = S - 2*sum_k w2[k]/(Ea*Eh+1)
//   S = b2 + sum_k w2[k], computed by wave 0 at the tail.
// Tile 16i x 16j per block, 256 thr = 4 waves; kq = wave index (SGPR) so
// w2 reads are scalar; thread = 2i x 2j x 128k; pair-rcp.
// 1152 blocks; XCD-swizzle: xcd = bid&7 owns b in [4*xcd, +4) -- the same
// rows gemm wrote on that XCD -> Ea/Eh are L2 hits.
// ---------------------------------------------------------------------------
__global__ __launch_bounds__(256) void arc_kernel(const _Float16* __restrict__ Ea,
                                                  const _Float16* __restrict__ Eh,
                                                  const float* __restrict__ w2,
                                                  const float* __restrict__ b2,
                                                  float* __restrict__ out) {
    __shared__ _Float16 a_s[16 * 512];   // 16 KB
    __shared__ _Float16 h_s[16 * 512];   // 16 KB
    __shared__ float    red[3][64][4];   // 3 KB (waves 1..3 partials)

    int bid = blockIdx.x;                // 32 * 6 * 6 = 1152
    int xcd = bid & 7;
    int sub = bid >> 3;                  // 0..143
    int b   = xcd * 4 + sub / 36;
    int r   = sub % 36;
    int it  = r / 6;
    int jt  = r % 6;
    int tid = threadIdx.x;

    const _Float16* asrc = Ea + (b * NN + it * 16) * 512;
    const _Float16* hsrc = Eh + (b * NN + jt * 16) * 512;

    // stage 16 rows x 64 chunks = 1024 chunks per array, 4 per thread
#pragma unroll
    for (int p = 0; p < 4; ++p) {
        int idx = tid + p * 256;
        int row = idx >> 6, c = idx & 63;
        int cs = c ^ (row & 7);
        *(f32x4*)(a_s + row * 512 + cs * 8) = *(const f32x4*)(asrc + row * 512 + c * 8);
        *(f32x4*)(h_s + row * 512 + cs * 8) = *(const f32x4*)(hsrc + row * 512 + c * 8);
    }
    __syncthreads();

    int w  = tid >> 6;
    int kq = __builtin_amdgcn_readfirstlane(w);   // SGPR 0..3
    int l  = tid & 63;
    int pi = l >> 3;                     // i-pair 0..7
    int pj = l & 7;                      // j-pair 0..7
    int r0a = pi * 2, r1a = r0a + 1;
    int r0h = pj * 2, r1h = r0h + 1;

    const _Float16* a0 = a_s + r0a * 512 + kq * 128;
    const _Float16* a1 = a_s + r1a * 512 + kq * 128;
    const _Float16* h0 = h_s + r0h * 512 + kq * 128;
    const _Float16* h1 = h_s + r1h * 512 + kq * 128;
    int sa0 = r0a & 7, sa1 = r1a & 7, sh0 = r0h & 7, sh1 = r1h & 7;
    const float* wp = w2 + kq * 128;     // uniform -> s_load

    float acc00 = 0.f, acc01 = 0.f, acc10 = 0.f, acc11 = 0.f;

#define PROC(av, hv, acc)                                                     \
    {                                                                         \
        float s0 = __builtin_fmaf((float)av[0], (float)hv[0], 1.0f);          \
        float s1 = __builtin_fmaf((float)av[1], (float)hv[1], 1.0f);          \
        float s2 = __builtin_fmaf((float)av[2], (float)hv[2], 1.0f);          \
        float s3 = __builtin_fmaf((float)av[3], (float)hv[3], 1.0f);          \
        float s4 = __builtin_fmaf((float)av[4], (float)hv[4], 1.0f);          \
        float s5 = __builtin_fmaf((float)av[5], (float)hv[5], 1.0f);          \
        float s6 = __builtin_fmaf((float)av[6], (float)hv[6], 1.0f);          \
        float s7 = __builtin_fmaf((float)av[7], (float)hv[7], 1.0f);          \
        float n0 = __builtin_fmaf(wv1, s0, wv0 * s1);                         \
        float n1 = __builtin_fmaf(wv3, s2, wv2 * s3);                         \
        float n2 = __builtin_fmaf(wv5, s4, wv4 * s5);                         \
        float n3 = __builtin_fmaf(wv7, s6, wv6 * s7);                         \
        acc = __builtin_fmaf(n0, __builtin_amdgcn_rcpf(s0 * s1), acc);        \
        acc = __builtin_fmaf(n1, __builtin_amdgcn_rcpf(s2 * s3), acc);        \
        acc = __builtin_fmaf(n2, __builtin_amdgcn_rcpf(s4 * s5), acc);        \
        acc = __builtin_fmaf(n3, __builtin_amdgcn_rcpf(s6 * s7), acc);        \
    }

#pragma unroll 4
    for (int c = 0; c < 16; ++c) {
        half8 av0 = *(const half8*)(a0 + ((c ^ sa0) << 3));
        half8 av1 = *(const half8*)(a1 + ((c ^ sa1) << 3));
        half8 hv0 = *(const half8*)(h0 + ((c ^ sh0) << 3));
        half8 hv1 = *(const half8*)(h1 + ((c ^ sh1) << 3));
        f32x4 wlo = *(const f32x4*)(wp + c * 8);
        f32x4 whi = *(const f32x4*)(wp + c * 8 + 4);
        float wv0 = wlo[0], wv1 = wlo[1], wv2 = wlo[2], wv3 = wlo[3];
        float wv4 = whi[0], wv5 = whi[1], wv6 = whi[2], wv7 = whi[3];
        PROC(av0, hv0, acc00)
        PROC(av0, hv1, acc01)
        PROC(av1, hv0, acc10)
        PROC(av1, hv1, acc11)
    }
#undef PROC

    if (w != 0) {
        f32x4 v = {acc00, acc01, acc10, acc11};
        *(f32x4*)(&red[w - 1][l][0]) = v;
    }
    __syncthreads();

    if (w == 0) {
#pragma unroll
        for (int rr = 0; rr < 3; ++rr) {
            f32x4 v = *(const f32x4*)(&red[rr][l][0]);
            acc00 += v[0]; acc01 += v[1]; acc10 += v[2]; acc11 += v[3];
        }
        // S = b2 + sum(w2): 8 elems/lane + butterfly (all lanes get total)
        f32x4 v0 = *(const f32x4*)(w2 + l * 8);
        f32x4 v1 = *(const f32x4*)(w2 + l * 8 + 4);
        float sv = (v0[0] + v0[1]) + (v0[2] + v0[3])
                 + (v1[0] + v1[1]) + (v1[2] + v1[3]);
#pragma unroll
        for (int off = 32; off; off >>= 1) sv += __shfl_xor(sv, off, 64);
        float Sv = sv + b2[0];

        int i0 = it * 16 + r0a;
        int j0 = jt * 16 + r0h;
        f32x2 o0 = {__builtin_fmaf(-2.f, acc00, Sv), __builtin_fmaf(-2.f, acc01, Sv)};
        f32x2 o1 = {__builtin_fmaf(-2.f, acc10, Sv), __builtin_fmaf(-2.f, acc11, Sv)};
        *(f32x2*)(out + (b * NN + i0) * NN + j0)     = o0;
        *(f32x2*)(out + (b * NN + i0 + 1) * NN + j0) = o1;
    }
}

// ---------------------------------------------------------------------------
extern "C" void kernel_launch(void* const* d_in, const int* in_sizes, int n_in,
                              void* d_out, int out_size, void* d_ws, size_t ws_size,
                              hipStream_t stream) {
    (void)in_sizes; (void)n_in; (void)out_size; (void)ws_size;

    const float* X  = (const float*)d_in[0];   // (32, 96, 512)
    const float* W1 = (const float*)d_in[1];   // (512, 1024)
    const float* b1 = (const float*)d_in[2];   // (512,)
    const float* W2 = (const float*)d_in[3];   // (1, 512)
    const float* b2 = (const float*)d_in[4];   // (1,)
    float* out = (float*)d_out;                // (32, 96, 96)

    char* ws = (char*)d_ws;
    _Float16* Ea = (_Float16*)(ws);                // 3,145,728 B
    _Float16* Eh = (_Float16*)(ws + 3145728);      // 3,145,728 B

    gemm_h<<<192, 512, 0, stream>>>(X, W1, b1, Ea, Eh);
    arc_kernel<<<1152, 256, 0, stream>>>(Ea, Eh, W2, b2, out);
}